// Round 11
// baseline (238.357 us; speedup 1.0000x reference)
//
#include <hip/hip_runtime.h>
#include <stdint.h>

#define BATCH   8
#define NPTS    8192
#define SCH     1024
#define KNN     32
#define TOPC    5
#define MAXIT   16
#define NCELL   4096     // 16^3 morton cells
#define NGRP    128      // groups of 64 per batch
#define NSEED   6        // cold-path seed groups scanned in mind2 order
#define FCAP    128      // collect-fallback LDS capacity (keys <= tau)

typedef unsigned long long ull;
typedef float vf2 __attribute__((ext_vector_type(2)));
typedef float vf4 __attribute__((ext_vector_type(4)));

// sentinel: unpacks to +inf d2, never enters top-32
#define SENTKEY ((((ull)0x7F800000u) << 13) | 0x1FFFull)

// rotated intra-group lane assignment (round-8 proven: fallback ~8% -> ~1-2%)
#define ROTL(lane, g) (((lane) + (g) * 17) & 63)

// order-preserving float<->u32 encode for atomicMin/Max bbox accumulation
__device__ __forceinline__ uint32_t fenc(float f) {
    uint32_t b = __float_as_uint(f);
    return (b & 0x80000000u) ? ~b : (b | 0x80000000u);
}
__device__ __forceinline__ float fdec(uint32_t u) {
    uint32_t b = (u & 0x80000000u) ? (u & 0x7FFFFFFFu) : ~u;
    return __uint_as_float(b);
}

// ---------------------------------------------------------------------------
// Cross-lane xor exchange: xor-1/xor-2 via DPP quad_perm (VALU pipe).
// ---------------------------------------------------------------------------
__device__ __forceinline__ uint32_t xshfl32(uint32_t v, int xl) {
    if (xl == 1)
        return (uint32_t)__builtin_amdgcn_update_dpp((int)v, (int)v, 0xB1, 0xF, 0xF, true);
    if (xl == 2)
        return (uint32_t)__builtin_amdgcn_update_dpp((int)v, (int)v, 0x4E, 0xF, 0xF, true);
    return (uint32_t)__shfl_xor((int)v, xl, 64);
}
__device__ __forceinline__ ull xshfl64(ull v, int xl) {
    uint32_t lo = xshfl32((uint32_t)v, xl);
    uint32_t hi = xshfl32((uint32_t)(v >> 32), xl);
    return ((ull)hi << 32) | lo;
}
__device__ __forceinline__ float xshflf(float v, int xl) {
    return __uint_as_float(xshfl32(__float_as_uint(v), xl));
}

// ---------------------------------------------------------------------------
// Exact d2: separate mul/add roundings (no FMA), order ((dx2+dy2)+dz2) = numpy.
// ---------------------------------------------------------------------------
__device__ __forceinline__ float d2_exact(vf4 q, vf4 p) {
#pragma clang fp contract(off)
    vf2 d = q.xy - p.xy;
    vf2 s = d * d;
    float dz = q.z - p.z;
    float sz = dz * dz;
    return (s.x + s.y) + sz;
}

__device__ __forceinline__ void insert_top4(ull key, ull& k0, ull& k1, ull& k2,
                                            ull& k3, float& th) {
    if (key < k3) {
        k3 = key;
        { bool c = k3 < k2; ull mn = c ? k3 : k2, mx = c ? k2 : k3; k2 = mn; k3 = mx; }
        { bool c = k2 < k1; ull mn = c ? k2 : k1, mx = c ? k1 : k2; k1 = mn; k2 = mx; }
        { bool c = k1 < k0; ull mn = c ? k1 : k0, mx = c ? k0 : k1; k0 = mn; k1 = mx; }
        th = __uint_as_float((uint32_t)(k3 >> 13));
    }
}

__device__ __forceinline__ ull wave_min_u64(ull k) {
#pragma unroll
    for (int off = 32; off; off >>= 1) {
        ull o = xshfl64(k, off);
        k = o < k ? o : k;
    }
    return k;
}
__device__ __forceinline__ ull wave_max_u64(ull k) {
#pragma unroll
    for (int off = 32; off; off >>= 1) {
        ull o = xshfl64(k, off);
        k = o > k ? o : k;
    }
    return k;
}

// conservative squared min distance from q to [mn,mx] interval box.
// Subtraction rounding (<=1 ulp overestimate) absorbed by the 0.9999 factor.
__device__ __forceinline__ float bbox_mind2_mm(vf4 q, vf4 mn, vf4 mx) {
    float dx = fmaxf(fmaxf(mn.x - q.x, q.x - mx.x), 0.f);
    float dy = fmaxf(fmaxf(mn.y - q.y, q.y - mx.y), 0.f);
    float dz = fmaxf(fmaxf(mn.z - q.z, q.z - mx.z), 0.f);
    return (dx * dx + dy * dy + dz * dz) * 0.9999f;
}

// bitonic helpers (64-bit)
__device__ __forceinline__ ull cx(ull v, int xl, bool keepmin) {
    ull o = xshfl64(v, xl);
    return ((v < o) == keepmin) ? v : o;
}
__device__ __forceinline__ void cswap(ull& a, ull& b, bool up) {
    bool lt = a < b;
    ull mn = lt ? a : b, mx = lt ? b : a;
    a = up ? mn : mx;
    b = up ? mx : mn;
}

// bitonic helpers (32-bit)
__device__ __forceinline__ uint32_t cx32(uint32_t v, int xl, bool keepmin) {
    uint32_t o = xshfl32(v, xl);
    return ((v < o) == keepmin) ? v : o;
}
__device__ __forceinline__ void cswap32(uint32_t& a, uint32_t& b, bool up) {
    uint32_t mn = a < b ? a : b, mx = a < b ? b : a;
    a = up ? mn : mx;
    b = up ? mx : mn;
}

// full bitonic sort of 128 u32 keys, 2 regs/lane (element = 2*lane+reg).
__device__ __forceinline__ void sort128_u32(uint32_t& s0, uint32_t& s1, int lane) {
    cswap32(s0, s1, true);
    if (lane & 1) { uint32_t t = s0; s0 = s1; s1 = t; }
#pragma unroll
    for (int kk = 4; kk <= 128; kk <<= 1) {
        const bool up = (lane & (kk >> 1)) == 0;
#pragma unroll
        for (int d = kk >> 1; d >= 2; d >>= 1) {
            const int xl = d >> 1;
            const bool keepmin = (up == ((lane & xl) == 0));
            s0 = cx32(s0, xl, keepmin);
            s1 = cx32(s1, xl, keepmin);
        }
        cswap32(s0, s1, up);
    }
}

// same network, 64-bit keys (collect-fallback sort)
__device__ __forceinline__ void sort128_u64(ull& s0, ull& s1, int lane) {
    cswap(s0, s1, true);
    if (lane & 1) { ull t = s0; s0 = s1; s1 = t; }
#pragma unroll
    for (int kk = 4; kk <= 128; kk <<= 1) {
        const bool up = (lane & (kk >> 1)) == 0;
#pragma unroll
        for (int d = kk >> 1; d >= 2; d >>= 1) {
            const int xl = d >> 1;
            const bool keepmin = (up == ((lane & xl) == 0));
            s0 = cx(s0, xl, keepmin);
            s1 = cx(s1, xl, keepmin);
        }
        cswap(s0, s1, up);
    }
}

// pop next selected group id from the wave-uniform pair of masks
__device__ __forceinline__ int next_gid(ull& r0, ull& r1) {
    if (r0) { int g = __ffsll((unsigned long long)r0) - 1; r0 &= r0 - 1; return g; }
    if (r1) { int g = __ffsll((unsigned long long)r1) - 1; r1 &= r1 - 1; return 64 + g; }
    return -1;
}

// morton cell id from point (16^3 over [-4,4], clamped)
__device__ __forceinline__ int cell_of(float x, float y, float z) {
    int cxi = min(15, max(0, (int)floorf((x + 4.0f) * 2.0f)));
    int cyi = min(15, max(0, (int)floorf((y + 4.0f) * 2.0f)));
    int czi = min(15, max(0, (int)floorf((z + 4.0f) * 2.0f)));
    uint32_t sx = (cxi & 1) | ((cxi & 2) << 2) | ((cxi & 4) << 4) | ((cxi & 8) << 6);
    uint32_t sy = (cyi & 1) | ((cyi & 2) << 2) | ((cyi & 4) << 4) | ((cyi & 8) << 6);
    uint32_t sz = (czi & 1) | ((czi & 2) << 2) | ((czi & 4) << 4) | ((czi & 8) << 6);
    return (int)(sx | (sy << 1) | (sz << 2));
}

// ---------------------------------------------------------------------------
// Backstop fallback (ultra-rare): exact serial extraction with refills.
// ---------------------------------------------------------------------------
__device__ __attribute__((noinline)) int serial_topk_masked(
    const vf4* __restrict__ Psort, vf4 q, int lane, ull sm0, ull sm1) {
    ull k0 = SENTKEY, k1 = SENTKEY, k2 = SENTKEY, k3 = SENTKEY;
    int s0 = 0, s1 = 0, s2 = 0, s3 = 0;
    float th = __builtin_inff();
    for (int gid = 0; gid < NGRP; ++gid) {
        bool sel = (gid < 64) ? ((sm0 >> gid) & 1ull) : ((sm1 >> (gid - 64)) & 1ull);
        if (!sel) continue;
        vf4 p = Psort[(gid << 6) + lane];
        float d2 = d2_exact(q, p);
        uint32_t oi = __float_as_uint(p.w);
        ull key = ((ull)__float_as_uint(d2) << 13) | oi;
        if (d2 <= th && key < k3) {
            k3 = key; s3 = gid;
            if (k3 < k2) { ull t = k2; k2 = k3; k3 = t; int ts = s2; s2 = s3; s3 = ts; }
            if (k2 < k1) { ull t = k1; k1 = k2; k2 = t; int ts = s1; s1 = s2; s2 = ts; }
            if (k1 < k0) { ull t = k0; k0 = k1; k1 = t; int ts = s0; s0 = s1; s1 = ts; }
            th = __uint_as_float((uint32_t)(k3 >> 13));
        }
    }
    ull em0 = 0ull, em1 = 0ull;
    int cnt = 4, my_ind = 0;
    for (int r = 0; r < KNN; ++r) {
        ull gmin = wave_min_u64(k0);
        int widx = (int)(gmin & 0x1FFFull);
        if (lane == r) my_ind = widx;
        if (k0 == gmin) {
            int g = s0;
            if (g < 64) em0 |= 1ull << g; else em1 |= 1ull << (g - 64);
            k0 = k1; k1 = k2; k2 = k3; k3 = SENTKEY;
            s0 = s1; s1 = s2; s2 = s3;
            if (--cnt == 0) {
                k0 = k1 = k2 = k3 = SENTKEY;
                float th2 = __builtin_inff();
                for (int gid = 0; gid < NGRP; ++gid) {
                    bool sel = (gid < 64) ? ((sm0 >> gid) & 1ull)
                                          : ((sm1 >> (gid - 64)) & 1ull);
                    bool ex = (gid < 64) ? ((em0 >> gid) & 1ull)
                                         : ((em1 >> (gid - 64)) & 1ull);
                    if (!sel || ex) continue;
                    vf4 p = Psort[(gid << 6) + lane];
                    float d2 = d2_exact(q, p);
                    uint32_t oi = __float_as_uint(p.w);
                    ull key = ((ull)__float_as_uint(d2) << 13) | oi;
                    if (d2 <= th2 && key < k3) {
                        k3 = key; s3 = gid;
                        if (k3 < k2) { ull t = k2; k2 = k3; k3 = t; int ts = s2; s2 = s3; s3 = ts; }
                        if (k2 < k1) { ull t = k1; k1 = k2; k2 = t; int ts = s1; s1 = s2; s2 = ts; }
                        if (k1 < k0) { ull t = k0; k0 = k1; k1 = t; int ts = s0; s0 = s1; s1 = ts; }
                        th2 = __uint_as_float((uint32_t)(k3 >> 13));
                    }
                }
                cnt = 4;
            }
        }
    }
    return my_ind;
}

// ---------------------------------------------------------------------------
// Cheap exact fallback (round-8 proven): collect all keys <= tau, sort 128.
// ---------------------------------------------------------------------------
__device__ int collect_topk(const vf4* __restrict__ Psort, vf4 q, int lane,
                            ull sm0, ull sm1, ull tau,
                            ull* buf, int* cnt) {
    if (lane == 0) *cnt = 0;
    __asm__ volatile("s_waitcnt lgkmcnt(0)" ::: "memory");
    ull r0 = sm0, r1 = sm1;
    int g = next_gid(r0, r1);
    while (g >= 0) {
        vf4 p = Psort[(g << 6) + lane];
        float d2 = d2_exact(q, p);
        ull key = ((ull)__float_as_uint(d2) << 13) | __float_as_uint(p.w);
        if (key <= tau) {
            int pos = atomicAdd(cnt, 1);
            if (pos < FCAP) buf[pos] = key;
        }
        g = next_gid(r0, r1);
    }
    __asm__ volatile("s_waitcnt lgkmcnt(0)" ::: "memory");
    const int M = *cnt;          // wave-uniform
    if (M > FCAP) return -1;
    ull s0 = (2 * lane + 0 < M) ? buf[2 * lane + 0] : SENTKEY;
    ull s1 = (2 * lane + 1 < M) ? buf[2 * lane + 1] : SENTKEY;
    sort128_u64(s0, s1, lane);
    const int src = lane >> 1;
    const uint32_t e0 = (uint32_t)__shfl((int)(uint32_t)s0, src, 64);
    const uint32_t e1 = (uint32_t)__shfl((int)(uint32_t)s1, src, 64);
    return (int)(((lane & 1) ? e1 : e0) & 0x1FFFu);
}

// ---------------------------------------------------------------------------
// Build phase: parallel multi-kernel, bbox folded into scatter via encoded
// atomicMin/Max (bbox_kernel removed). One-block-per-batch fusion refuted
// twice (rounds 5/6, 8) — build stays on wide grids.
// ---------------------------------------------------------------------------
__global__ __launch_bounds__(256) void prep_kernel(const float* __restrict__ xyz,
                                                   vf4* __restrict__ pc4,
                                                   int* __restrict__ counts,
                                                   uint32_t* __restrict__ bMinU,
                                                   uint32_t* __restrict__ bMaxU) {
    int i = (int)(blockIdx.x * blockDim.x + threadIdx.x);
    if (i >= BATCH * NPTS) return;
    if (i < BATCH * NGRP * 3) { bMinU[i] = 0xFFFFFFFFu; bMaxU[i] = 0u; }
    vf4 v;
    v.x = xyz[(size_t)i * 3 + 0];
    v.y = xyz[(size_t)i * 3 + 1];
    v.z = xyz[(size_t)i * 3 + 2];
    v.w = 0.f;
    pc4[i] = v;
    int b = i >> 13;
    atomicAdd(&counts[b * NCELL + cell_of(v.x, v.y, v.z)], 1);
}

__global__ __launch_bounds__(1024) void scan_kernel(const int* __restrict__ counts,
                                                    int* __restrict__ cursor) {
    int b = (int)blockIdx.x, tid = (int)threadIdx.x;
    int lane = tid & 63, w = tid >> 6;
    __shared__ int wsum[16];
    int base = b * NCELL + tid * 4;
    int v0 = counts[base], v1 = counts[base + 1], v2 = counts[base + 2], v3 = counts[base + 3];
    int s = v0 + v1 + v2 + v3;
    int incl = s;
#pragma unroll
    for (int off = 1; off < 64; off <<= 1) {
        int o = __shfl_up(incl, off, 64);
        if (lane >= off) incl += o;
    }
    if (lane == 63) wsum[w] = incl;
    __syncthreads();
    if (tid == 0) {
        int acc = 0;
#pragma unroll
        for (int i = 0; i < 16; ++i) { int x = wsum[i]; wsum[i] = acc; acc += x; }
    }
    __syncthreads();
    int excl = incl - s + wsum[w];
    cursor[base]     = excl;
    cursor[base + 1] = excl + v0;
    cursor[base + 2] = excl + v0 + v1;
    cursor[base + 3] = excl + v0 + v1 + v2;
}

__global__ __launch_bounds__(256) void scatter_kernel(const vf4* __restrict__ pc4,
                                                      int* __restrict__ cursor,
                                                      vf4* __restrict__ sortedP,
                                                      uint32_t* __restrict__ bMinU,
                                                      uint32_t* __restrict__ bMaxU) {
    int i = (int)(blockIdx.x * blockDim.x + threadIdx.x);
    if (i >= BATCH * NPTS) return;
    vf4 v = pc4[i];
    int b = i >> 13, pi = i & (NPTS - 1);
    int c = cell_of(v.x, v.y, v.z);
    int pos = atomicAdd(&cursor[b * NCELL + c], 1);
    // group bbox accumulation: group id known from sorted position
    const int g = ((b << 7) + (pos >> 6)) * 3;
    atomicMin(&bMinU[g + 0], fenc(v.x));
    atomicMin(&bMinU[g + 1], fenc(v.y));
    atomicMin(&bMinU[g + 2], fenc(v.z));
    atomicMax(&bMaxU[g + 0], fenc(v.x));
    atomicMax(&bMaxU[g + 1], fenc(v.y));
    atomicMax(&bMaxU[g + 2], fenc(v.z));
    v.w = __uint_as_float((uint32_t)pi);
    sortedP[((size_t)b << 13) + pos] = v;
}

// ---------------------------------------------------------------------------
// Main refine: one wave per chain (round-8 logic frozen), plus fused ordering:
// the last block of each batch (device-scope atomic + fences, G16) computes
// the stable (conv, s) rank via per-bin 1024-bit masks and writes `out`.
// ---------------------------------------------------------------------------
__global__ __launch_bounds__(256)
__attribute__((amdgpu_waves_per_eu(2, 4)))
void refine_kernel(
    const vf4* __restrict__ pc4, const vf4* __restrict__ sortedP,
    const uint32_t* __restrict__ bMinU, const uint32_t* __restrict__ bMaxU,
    const float* __restrict__ center, const int* __restrict__ idx_in,
    float* __restrict__ pts_ws, int* __restrict__ idx_ws,
    int* __restrict__ grp_ws, int* __restrict__ conv_ws,
    float* __restrict__ out, int* __restrict__ done) {
    const int lane = (int)(threadIdx.x & 63);
    const int w = (int)(threadIdx.x >> 6);
    const int b = (int)(blockIdx.x & 7);                  // XCD-aligned batch
    const int s = (((int)blockIdx.x >> 3) << 2) + w;      // chain within batch
    const vf4* __restrict__ Porig = pc4 + ((size_t)b << 13);
    const vf4* __restrict__ Psort = sortedP + ((size_t)b << 13);

    __shared__ vf4 sMn[NGRP], sMx[NGRP];
    __shared__ vf4 nbh[4][KNN];
    __shared__ ull fbuf[4][FCAP];
    __shared__ int fcnt[4];
    __shared__ ull binmask[MAXIT + 1][16];   // fused-order: 1024 bits per bin
    __shared__ int binbase2[MAXIT + 1];
    __shared__ int lastflag;

    // stage + decode the batch's 128 group bboxes into LDS
    {
        const int t = (int)threadIdx.x;
        if (t < NGRP) {
            const int gi = ((b << 7) + t) * 3;
            vf4 v;
            v.x = fdec(bMinU[gi + 0]); v.y = fdec(bMinU[gi + 1]);
            v.z = fdec(bMinU[gi + 2]); v.w = 0.f;
            sMn[t] = v;
        } else {
            const int tt = t - NGRP;
            const int gi = ((b << 7) + tt) * 3;
            vf4 v;
            v.x = fdec(bMaxU[gi + 0]); v.y = fdec(bMaxU[gi + 1]);
            v.z = fdec(bMaxU[gi + 2]); v.w = 0.f;
            sMx[tt] = v;
        }
    }
    __syncthreads();

    const size_t ch = ((size_t)b << 10) + (size_t)s;
    vf4 q;
    q.x = center[ch * 3 + 0];
    q.y = center[ch * 3 + 1];
    q.z = center[ch * 3 + 2];
    q.w = 0.f;
    int qidx = idx_in[ch];

    int conv = MAXIT;
    int my_ind = 0;
    vf4 myp = q;           // lanes<KNN: previous iteration's neighbor point
    bool warm = false;

    for (int it = 0;; ++it) {
        const float m0 = bbox_mind2_mm(q, sMn[lane], sMx[lane]);
        const float m1 = bbox_mind2_mm(q, sMn[64 + lane], sMx[64 + lane]);

        ull k0 = SENTKEY, k1 = SENTKEY, k2 = SENTKEY, k3 = SENTKEY;
        float th = __builtin_inff();
        ull sm0 = 0ull, sm1 = 0ull, am0 = 0ull, am1 = 0ull;
        float th0 = __builtin_inff();

        bool fastwarm = false;
        if (warm) {
            const float dw = (lane < KNN) ? d2_exact(q, myp) : 0.f;
            th0 = dw;
#pragma unroll
            for (int off = 32; off; off >>= 1)
                th0 = fmaxf(th0, xshflf(th0, off));
            sm0 = __ballot(m0 <= th0);
            sm1 = __ballot(m1 <= th0);
            const int nsel = __popcll(sm0) + __popcll(sm1);
            if (nsel <= 20) { fastwarm = true; am0 = sm0; am1 = sm1; }
        }

        if (!fastwarm) {
            // ---- sorted seed path (cold / fat-warm) ----
            sm0 = 0ull; sm1 = 0ull;
            uint32_t g0k = ((__float_as_uint(m0) >> 6) << 7) | (uint32_t)lane;
            uint32_t g1k = ((__float_as_uint(m1) >> 6) << 7) | (uint32_t)(64 + lane);
            sort128_u32(g0k, g1k, lane);
#pragma unroll
            for (int r = 0; r < NSEED; ++r) {
                const uint32_t nk = (r & 1)
                    ? (uint32_t)__shfl((int)g1k, r >> 1, 64)
                    : (uint32_t)__shfl((int)g0k, r >> 1, 64);
                const int gid = (int)(nk & 127u);
                if (gid < 64) sm0 |= 1ull << gid; else sm1 |= 1ull << (gid - 64);
                const vf4 p = Psort[(gid << 6) + ROTL(lane, gid)];
                const float d2 = d2_exact(q, p);
                if (d2 <= th)
                    insert_top4(((ull)__float_as_uint(d2) << 13) | __float_as_uint(p.w),
                                k0, k1, k2, k3, th);
            }
            // sound UB on 32nd-smallest: max of 32 distinct pairwise-min keys
            ull t = k0;
            {
                ull o = xshfl64(t, 32);
                t = o < t ? o : t;
            }
            const ull B = wave_max_u64(t);
            const float Bd = fminf(__uint_as_float((uint32_t)(B >> 13)), th0);
            am0 = __ballot(m0 <= Bd) & ~sm0;
            am1 = __ballot(m1 <= Bd) & ~sm1;
            sm0 |= am0; sm1 |= am1;
        }

        // ---- masked scan of remaining groups, 2-way unrolled ----
        {
            ull rem0 = am0, rem1 = am1;
            int ga = next_gid(rem0, rem1);
            while (ga >= 0) {
                const int gb2 = next_gid(rem0, rem1);
                const vf4 pa = Psort[(ga << 6) + ROTL(lane, ga)];
                vf4 pb;
                if (gb2 >= 0) pb = Psort[(gb2 << 6) + ROTL(lane, gb2)];
                const float da = d2_exact(q, pa);
                if (da <= th)
                    insert_top4(((ull)__float_as_uint(da) << 13) | __float_as_uint(pa.w),
                                k0, k1, k2, k3, th);
                if (gb2 >= 0) {
                    const float dbv = d2_exact(q, pb);
                    if (dbv <= th)
                        insert_top4(((ull)__float_as_uint(dbv) << 13) | __float_as_uint(pb.w),
                                    k0, k1, k2, k3, th);
                }
                ga = next_gid(rem0, rem1);
            }
        }
        const ull prek3 = k3;

        // ---- wave bitonic sort of 256 candidates (sentinel-padded) ----
        const bool odd = (lane & 1) != 0;
        ull a0 = odd ? k3 : k0;
        ull a1 = odd ? k2 : k1;
        ull a2 = odd ? k1 : k2;
        ull a3 = odd ? k0 : k3;
#pragma unroll
        for (int kk = 8; kk <= 256; kk <<= 1) {
            const bool up = (lane & (kk >> 2)) == 0;
#pragma unroll
            for (int d = kk >> 1; d >= 4; d >>= 1) {
                const int xl = d >> 2;
                const bool keepmin = (up == ((lane & xl) == 0));
                a0 = cx(a0, xl, keepmin);
                a1 = cx(a1, xl, keepmin);
                a2 = cx(a2, xl, keepmin);
                a3 = cx(a3, xl, keepmin);
            }
            cswap(a0, a2, up); cswap(a1, a3, up);
            cswap(a0, a1, up); cswap(a2, a3, up);
        }
        // rank r lives at lane r>>2, reg r&3; tau = rank-31 key
        const ull tau = (ull)__shfl((unsigned long long)a3, 7, 64);
        const ull bad = __ballot(prek3 < tau);
        if (bad != 0ull) {
            const int mi = collect_topk(Psort, q, lane, sm0, sm1, tau,
                                        fbuf[w], &fcnt[w]);
            my_ind = (mi >= 0) ? mi : serial_topk_masked(Psort, q, lane, sm0, sm1);
        } else {
            const int src = lane >> 2;
            const uint32_t lo0 = (uint32_t)__shfl((int)(uint32_t)a0, src, 64);
            const uint32_t lo1 = (uint32_t)__shfl((int)(uint32_t)a1, src, 64);
            const uint32_t lo2 = (uint32_t)__shfl((int)(uint32_t)a2, src, 64);
            const uint32_t lo3 = (uint32_t)__shfl((int)(uint32_t)a3, src, 64);
            const int sel = lane & 3;
            uint32_t lo = (sel == 0) ? lo0 : (sel == 1) ? lo1 : (sel == 2) ? lo2 : lo3;
            my_ind = (int)(lo & 0x1FFFu);
        }

        if (it == MAXIT) break;  // final step's ind recorded; conv stays MAXIT

        // ---- centroid: stage 32 ordered neighbors to LDS, sequential fold ----
        myp = q;
        if (lane < KNN) {
            myp = Porig[my_ind];
            nbh[w][lane] = myp;
        }
        __asm__ volatile("s_waitcnt lgkmcnt(0)" ::: "memory");
        float sx = 0.f, sy = 0.f, sz = 0.f;
#pragma unroll
        for (int j = 0; j < KNN; ++j) {
            vf4 pj = nbh[w][j];
            sx = __fadd_rn(sx, pj.x);
            sy = __fadd_rn(sy, pj.y);
            sz = __fadd_rn(sz, pj.z);
        }
        const float gx = __fmul_rn(sx, 0.03125f);
        const float gy = __fmul_rn(sy, 0.03125f);
        const float gz = __fmul_rn(sz, 0.03125f);

        // ---- per-neighbor distance to centroid (post-sqrt ordering) ----
        float dj = __builtin_inff();
        if (lane < KNN) {
            const float dx = __fsub_rn(myp.x, gx);
            const float dy = __fsub_rn(myp.y, gy);
            const float dz = __fsub_rn(myp.z, gz);
            dj = sqrtf(__fadd_rn(__fadd_rn(__fmul_rn(dx, dx), __fmul_rn(dy, dy)),
                                 __fmul_rn(dz, dz)));
        }
        const uint32_t db = __float_as_uint(dj);  // nonneg: bit order == fp order
        const uint32_t d0 = (uint32_t)__shfl((int)db, 0, 64);
        const ull bal = __ballot(db < d0);
        if (__popcll(bal) <= TOPC - 1) { conv = it; break; }

        // move target: lexicographic argmin of (dist, j)
        uint32_t m = db;
#pragma unroll
        for (int off = 32; off; off >>= 1) {
            uint32_t o = xshfl32(m, off);
            m = o < m ? o : m;
        }
        const ull balm = __ballot(db == m);
        const int jm = __ffsll((unsigned long long)balm) - 1;
        qidx = __shfl(my_ind, jm, 64);
        q.x = __shfl(myp.x, jm, 64);
        q.y = __shfl(myp.y, jm, 64);
        q.z = __shfl(myp.z, jm, 64);
        q.w = 0.f;
        warm = true;
    }

    if (lane < KNN) grp_ws[ch * KNN + lane] = my_ind;
    if (lane == 0) {
        pts_ws[ch * 3 + 0] = q.x;
        pts_ws[ch * 3 + 1] = q.y;
        pts_ws[ch * 3 + 2] = q.z;
        idx_ws[ch] = qidx;
        conv_ws[ch] = conv;
    }

    // ======== fused ordering: last block of the batch does it ========
    __syncthreads();
    if (threadIdx.x == 0) {
        __threadfence();                       // release our chains' results
        const int prev = atomicAdd(&done[b], 1);
        lastflag = (prev == (SCH / 4) - 1);    // 256 blocks per batch
    }
    __syncthreads();
    if (!lastflag) return;
    __threadfence();                           // acquire all blocks' results

    const int t = (int)threadIdx.x;
    for (int i = t; i < (MAXIT + 1) * 16; i += 256)
        ((ull*)binmask)[i] = 0ull;
    __syncthreads();
    int cvals[4];
#pragma unroll
    for (int pass = 0; pass < 4; ++pass) {
        const int s2 = pass * 256 + t;
        const int c = conv_ws[((size_t)b << 10) + s2];
        cvals[pass] = c;
        atomicOr(&binmask[c][s2 >> 6], 1ull << (s2 & 63));
    }
    __syncthreads();
    if (t == 0) {
        int acc = 0;
        for (int v = 0; v <= MAXIT; ++v) {
            int cnt2 = 0;
            for (int w2 = 0; w2 < 16; ++w2) cnt2 += (int)__popcll(binmask[v][w2]);
            binbase2[v] = acc;
            acc += cnt2;
        }
    }
    __syncthreads();
    float* __restrict__ C  = out;                              // (B,S,3)
    float* __restrict__ I1 = out + (size_t)BATCH * SCH * 3;    // (B,S)
    float* __restrict__ I2 = I1 + (size_t)BATCH * SCH;         // (B,S,K)
#pragma unroll
    for (int pass = 0; pass < 4; ++pass) {
        const int s2 = pass * 256 + t;
        const int c = cvals[pass];
        int r = 0;
        for (int w2 = 0; w2 < (s2 >> 6); ++w2) r += (int)__popcll(binmask[c][w2]);
        r += (int)__popcll(binmask[c][s2 >> 6] & ((1ull << (s2 & 63)) - 1ull));
        const int pos = binbase2[c] + r;
        const size_t chs = ((size_t)b << 10) + s2;
        const size_t o = ((size_t)b << 10) + pos;
        C[o * 3 + 0] = pts_ws[chs * 3 + 0];
        C[o * 3 + 1] = pts_ws[chs * 3 + 1];
        C[o * 3 + 2] = pts_ws[chs * 3 + 2];
        I1[o] = (float)idx_ws[chs];
        for (int k = 0; k < KNN; ++k)
            I2[o * KNN + k] = (float)grp_ws[chs * KNN + k];
    }
}

extern "C" void kernel_launch(void* const* d_in, const int* in_sizes, int n_in,
                              void* d_out, int out_size, void* d_ws, size_t ws_size,
                              hipStream_t stream) {
    const float* xyz    = (const float*)d_in[0];  // (8,8192,3) f32
    const float* center = (const float*)d_in[1];  // (8,1024,3) f32
    const int*   idx_in = (const int*)d_in[2];    // (8,1024)   i32
    float* out = (float*)d_out;

    // workspace layout (~3.5 MB)
    char* wp = (char*)d_ws;
    vf4* pc4     = (vf4*)wp;  wp += (size_t)BATCH * NPTS * sizeof(vf4);   // 1 MB
    vf4* sortedP = (vf4*)wp;  wp += (size_t)BATCH * NPTS * sizeof(vf4);   // 1 MB
    uint32_t* bMinU = (uint32_t*)wp; wp += (size_t)BATCH * NGRP * 3 * 4;  // 12 KB
    uint32_t* bMaxU = (uint32_t*)wp; wp += (size_t)BATCH * NGRP * 3 * 4;  // 12 KB
    int* counts  = (int*)wp;  wp += (size_t)BATCH * NCELL * 4;            // 128 KB
    int* done    = (int*)wp;  wp += 32;                                   // 8 ints (zeroed w/ counts)
    int* cursor  = (int*)wp;  wp += (size_t)BATCH * NCELL * 4;            // 128 KB
    float* pts_ws = (float*)wp; wp += (size_t)BATCH * SCH * 3 * 4;
    int*   idx_ws = (int*)wp;   wp += (size_t)BATCH * SCH * 4;
    int*   grp_ws = (int*)wp;   wp += (size_t)BATCH * SCH * KNN * 4;      // 1 MB
    int*   conv_ws = (int*)wp;

    hipMemsetAsync(counts, 0, (size_t)BATCH * NCELL * 4 + 32, stream);
    prep_kernel<<<(BATCH * NPTS + 255) / 256, 256, 0, stream>>>(
        xyz, pc4, counts, bMinU, bMaxU);
    scan_kernel<<<BATCH, 1024, 0, stream>>>(counts, cursor);
    scatter_kernel<<<(BATCH * NPTS + 255) / 256, 256, 0, stream>>>(
        pc4, cursor, sortedP, bMinU, bMaxU);

    const int chains = BATCH * SCH;                 // 8192 waves, 1 per chain
    refine_kernel<<<chains * 64 / 256, 256, 0, stream>>>(
        pc4, sortedP, bMinU, bMaxU, center, idx_in,
        pts_ws, idx_ws, grp_ws, conv_ws, out, done);
}

// Round 12
// 190.500 us; speedup vs baseline: 1.2512x; 1.2512x over previous
//
#include <hip/hip_runtime.h>
#include <stdint.h>

#define BATCH   8
#define NPTS    8192
#define SCH     1024
#define KNN     32
#define TOPC    5
#define MAXIT   16
#define NCELL   4096     // 16^3 morton cells
#define NGRP    128      // groups of 64 per batch
#define NSEED   6        // cold-path seed groups scanned in mind2 order
#define FCAP    128      // collect-fallback LDS capacity (keys <= tau)

typedef unsigned long long ull;
typedef float vf2 __attribute__((ext_vector_type(2)));
typedef float vf4 __attribute__((ext_vector_type(4)));

// sentinel: unpacks to +inf d2, never enters top-32
#define SENTKEY ((((ull)0x7F800000u) << 13) | 0x1FFFull)

// rotated intra-group lane assignment (round-8 proven: fallback ~8% -> ~1-2%)
#define ROTL(lane, g) (((lane) + (g) * 17) & 63)

// order-preserving float<->u32 encode for atomicMin/Max bbox accumulation
__device__ __forceinline__ uint32_t fenc(float f) {
    uint32_t b = __float_as_uint(f);
    return (b & 0x80000000u) ? ~b : (b | 0x80000000u);
}
__device__ __forceinline__ float fdec(uint32_t u) {
    uint32_t b = (u & 0x80000000u) ? (u & 0x7FFFFFFFu) : ~u;
    return __uint_as_float(b);
}

// ---------------------------------------------------------------------------
// Cross-lane xor exchange: xor-1/xor-2 via DPP quad_perm (VALU pipe).
// ---------------------------------------------------------------------------
__device__ __forceinline__ uint32_t xshfl32(uint32_t v, int xl) {
    if (xl == 1)
        return (uint32_t)__builtin_amdgcn_update_dpp((int)v, (int)v, 0xB1, 0xF, 0xF, true);
    if (xl == 2)
        return (uint32_t)__builtin_amdgcn_update_dpp((int)v, (int)v, 0x4E, 0xF, 0xF, true);
    return (uint32_t)__shfl_xor((int)v, xl, 64);
}
__device__ __forceinline__ ull xshfl64(ull v, int xl) {
    uint32_t lo = xshfl32((uint32_t)v, xl);
    uint32_t hi = xshfl32((uint32_t)(v >> 32), xl);
    return ((ull)hi << 32) | lo;
}
__device__ __forceinline__ float xshflf(float v, int xl) {
    return __uint_as_float(xshfl32(__float_as_uint(v), xl));
}

// ---------------------------------------------------------------------------
// Exact d2: separate mul/add roundings (no FMA), order ((dx2+dy2)+dz2) = numpy.
// ---------------------------------------------------------------------------
__device__ __forceinline__ float d2_exact(vf4 q, vf4 p) {
#pragma clang fp contract(off)
    vf2 d = q.xy - p.xy;
    vf2 s = d * d;
    float dz = q.z - p.z;
    float sz = dz * dz;
    return (s.x + s.y) + sz;
}

__device__ __forceinline__ void insert_top4(ull key, ull& k0, ull& k1, ull& k2,
                                            ull& k3, float& th) {
    if (key < k3) {
        k3 = key;
        { bool c = k3 < k2; ull mn = c ? k3 : k2, mx = c ? k2 : k3; k2 = mn; k3 = mx; }
        { bool c = k2 < k1; ull mn = c ? k2 : k1, mx = c ? k1 : k2; k1 = mn; k2 = mx; }
        { bool c = k1 < k0; ull mn = c ? k1 : k0, mx = c ? k0 : k1; k0 = mn; k1 = mx; }
        th = __uint_as_float((uint32_t)(k3 >> 13));
    }
}

__device__ __forceinline__ ull wave_min_u64(ull k) {
#pragma unroll
    for (int off = 32; off; off >>= 1) {
        ull o = xshfl64(k, off);
        k = o < k ? o : k;
    }
    return k;
}
__device__ __forceinline__ ull wave_max_u64(ull k) {
#pragma unroll
    for (int off = 32; off; off >>= 1) {
        ull o = xshfl64(k, off);
        k = o > k ? o : k;
    }
    return k;
}

// conservative squared min distance from q to [mn,mx] interval box.
// Subtraction rounding (<=1 ulp overestimate) absorbed by the 0.9999 factor.
__device__ __forceinline__ float bbox_mind2_mm(vf4 q, vf4 mn, vf4 mx) {
    float dx = fmaxf(fmaxf(mn.x - q.x, q.x - mx.x), 0.f);
    float dy = fmaxf(fmaxf(mn.y - q.y, q.y - mx.y), 0.f);
    float dz = fmaxf(fmaxf(mn.z - q.z, q.z - mx.z), 0.f);
    return (dx * dx + dy * dy + dz * dz) * 0.9999f;
}

// bitonic helpers (64-bit)
__device__ __forceinline__ ull cx(ull v, int xl, bool keepmin) {
    ull o = xshfl64(v, xl);
    return ((v < o) == keepmin) ? v : o;
}
__device__ __forceinline__ void cswap(ull& a, ull& b, bool up) {
    bool lt = a < b;
    ull mn = lt ? a : b, mx = lt ? b : a;
    a = up ? mn : mx;
    b = up ? mx : mn;
}

// bitonic helpers (32-bit)
__device__ __forceinline__ uint32_t cx32(uint32_t v, int xl, bool keepmin) {
    uint32_t o = xshfl32(v, xl);
    return ((v < o) == keepmin) ? v : o;
}
__device__ __forceinline__ void cswap32(uint32_t& a, uint32_t& b, bool up) {
    uint32_t mn = a < b ? a : b, mx = a < b ? b : a;
    a = up ? mn : mx;
    b = up ? mx : mn;
}

// full bitonic sort of 128 u32 keys, 2 regs/lane (element = 2*lane+reg).
__device__ __forceinline__ void sort128_u32(uint32_t& s0, uint32_t& s1, int lane) {
    cswap32(s0, s1, true);
    if (lane & 1) { uint32_t t = s0; s0 = s1; s1 = t; }
#pragma unroll
    for (int kk = 4; kk <= 128; kk <<= 1) {
        const bool up = (lane & (kk >> 1)) == 0;
#pragma unroll
        for (int d = kk >> 1; d >= 2; d >>= 1) {
            const int xl = d >> 1;
            const bool keepmin = (up == ((lane & xl) == 0));
            s0 = cx32(s0, xl, keepmin);
            s1 = cx32(s1, xl, keepmin);
        }
        cswap32(s0, s1, up);
    }
}

// same network, 64-bit keys (collect-fallback sort)
__device__ __forceinline__ void sort128_u64(ull& s0, ull& s1, int lane) {
    cswap(s0, s1, true);
    if (lane & 1) { ull t = s0; s0 = s1; s1 = t; }
#pragma unroll
    for (int kk = 4; kk <= 128; kk <<= 1) {
        const bool up = (lane & (kk >> 1)) == 0;
#pragma unroll
        for (int d = kk >> 1; d >= 2; d >>= 1) {
            const int xl = d >> 1;
            const bool keepmin = (up == ((lane & xl) == 0));
            s0 = cx(s0, xl, keepmin);
            s1 = cx(s1, xl, keepmin);
        }
        cswap(s0, s1, up);
    }
}

// pop next selected group id from the wave-uniform pair of masks
__device__ __forceinline__ int next_gid(ull& r0, ull& r1) {
    if (r0) { int g = __ffsll((unsigned long long)r0) - 1; r0 &= r0 - 1; return g; }
    if (r1) { int g = __ffsll((unsigned long long)r1) - 1; r1 &= r1 - 1; return 64 + g; }
    return -1;
}

// morton cell id from point (16^3 over [-4,4], clamped)
__device__ __forceinline__ int cell_of(float x, float y, float z) {
    int cxi = min(15, max(0, (int)floorf((x + 4.0f) * 2.0f)));
    int cyi = min(15, max(0, (int)floorf((y + 4.0f) * 2.0f)));
    int czi = min(15, max(0, (int)floorf((z + 4.0f) * 2.0f)));
    uint32_t sx = (cxi & 1) | ((cxi & 2) << 2) | ((cxi & 4) << 4) | ((cxi & 8) << 6);
    uint32_t sy = (cyi & 1) | ((cyi & 2) << 2) | ((cyi & 4) << 4) | ((cyi & 8) << 6);
    uint32_t sz = (czi & 1) | ((czi & 2) << 2) | ((czi & 4) << 4) | ((czi & 8) << 6);
    return (int)(sx | (sy << 1) | (sz << 2));
}

// ---------------------------------------------------------------------------
// Backstop fallback (ultra-rare): exact serial extraction with refills.
// ---------------------------------------------------------------------------
__device__ __attribute__((noinline)) int serial_topk_masked(
    const vf4* __restrict__ Psort, vf4 q, int lane, ull sm0, ull sm1) {
    ull k0 = SENTKEY, k1 = SENTKEY, k2 = SENTKEY, k3 = SENTKEY;
    int s0 = 0, s1 = 0, s2 = 0, s3 = 0;
    float th = __builtin_inff();
    for (int gid = 0; gid < NGRP; ++gid) {
        bool sel = (gid < 64) ? ((sm0 >> gid) & 1ull) : ((sm1 >> (gid - 64)) & 1ull);
        if (!sel) continue;
        vf4 p = Psort[(gid << 6) + lane];
        float d2 = d2_exact(q, p);
        uint32_t oi = __float_as_uint(p.w);
        ull key = ((ull)__float_as_uint(d2) << 13) | oi;
        if (d2 <= th && key < k3) {
            k3 = key; s3 = gid;
            if (k3 < k2) { ull t = k2; k2 = k3; k3 = t; int ts = s2; s2 = s3; s3 = ts; }
            if (k2 < k1) { ull t = k1; k1 = k2; k2 = t; int ts = s1; s1 = s2; s2 = ts; }
            if (k1 < k0) { ull t = k0; k0 = k1; k1 = t; int ts = s0; s0 = s1; s1 = ts; }
            th = __uint_as_float((uint32_t)(k3 >> 13));
        }
    }
    ull em0 = 0ull, em1 = 0ull;
    int cnt = 4, my_ind = 0;
    for (int r = 0; r < KNN; ++r) {
        ull gmin = wave_min_u64(k0);
        int widx = (int)(gmin & 0x1FFFull);
        if (lane == r) my_ind = widx;
        if (k0 == gmin) {
            int g = s0;
            if (g < 64) em0 |= 1ull << g; else em1 |= 1ull << (g - 64);
            k0 = k1; k1 = k2; k2 = k3; k3 = SENTKEY;
            s0 = s1; s1 = s2; s2 = s3;
            if (--cnt == 0) {
                k0 = k1 = k2 = k3 = SENTKEY;
                float th2 = __builtin_inff();
                for (int gid = 0; gid < NGRP; ++gid) {
                    bool sel = (gid < 64) ? ((sm0 >> gid) & 1ull)
                                          : ((sm1 >> (gid - 64)) & 1ull);
                    bool ex = (gid < 64) ? ((em0 >> gid) & 1ull)
                                         : ((em1 >> (gid - 64)) & 1ull);
                    if (!sel || ex) continue;
                    vf4 p = Psort[(gid << 6) + lane];
                    float d2 = d2_exact(q, p);
                    uint32_t oi = __float_as_uint(p.w);
                    ull key = ((ull)__float_as_uint(d2) << 13) | oi;
                    if (d2 <= th2 && key < k3) {
                        k3 = key; s3 = gid;
                        if (k3 < k2) { ull t = k2; k2 = k3; k3 = t; int ts = s2; s2 = s3; s3 = ts; }
                        if (k2 < k1) { ull t = k1; k1 = k2; k2 = t; int ts = s1; s1 = s2; s2 = ts; }
                        if (k1 < k0) { ull t = k0; k0 = k1; k1 = t; int ts = s0; s0 = s1; s1 = ts; }
                        th2 = __uint_as_float((uint32_t)(k3 >> 13));
                    }
                }
                cnt = 4;
            }
        }
    }
    return my_ind;
}

// ---------------------------------------------------------------------------
// Cheap exact fallback (round-8 proven): collect all keys <= tau, sort 128.
// ---------------------------------------------------------------------------
__device__ int collect_topk(const vf4* __restrict__ Psort, vf4 q, int lane,
                            ull sm0, ull sm1, ull tau,
                            ull* buf, int* cnt) {
    if (lane == 0) *cnt = 0;
    __asm__ volatile("s_waitcnt lgkmcnt(0)" ::: "memory");
    ull r0 = sm0, r1 = sm1;
    int g = next_gid(r0, r1);
    while (g >= 0) {
        vf4 p = Psort[(g << 6) + lane];
        float d2 = d2_exact(q, p);
        ull key = ((ull)__float_as_uint(d2) << 13) | __float_as_uint(p.w);
        if (key <= tau) {
            int pos = atomicAdd(cnt, 1);
            if (pos < FCAP) buf[pos] = key;
        }
        g = next_gid(r0, r1);
    }
    __asm__ volatile("s_waitcnt lgkmcnt(0)" ::: "memory");
    const int M = *cnt;          // wave-uniform
    if (M > FCAP) return -1;
    ull s0 = (2 * lane + 0 < M) ? buf[2 * lane + 0] : SENTKEY;
    ull s1 = (2 * lane + 1 < M) ? buf[2 * lane + 1] : SENTKEY;
    sort128_u64(s0, s1, lane);
    const int src = lane >> 1;
    const uint32_t e0 = (uint32_t)__shfl((int)(uint32_t)s0, src, 64);
    const uint32_t e1 = (uint32_t)__shfl((int)(uint32_t)s1, src, 64);
    return (int)(((lane & 1) ? e1 : e0) & 0x1FFFu);
}

// ---------------------------------------------------------------------------
// Build phase: parallel multi-kernel; bbox folded into scatter via encoded
// atomicMin/Max (fence-free). Fused cross-block ordering REFUTED (round 11:
// per-block device fences force L2 writebacks on non-coherent XCD L2s —
// WRITE_SIZE 5.3 -> 53 MB, refine +65 us). Separate order_kernel restored.
// ---------------------------------------------------------------------------
__global__ __launch_bounds__(256) void prep_kernel(const float* __restrict__ xyz,
                                                   vf4* __restrict__ pc4,
                                                   int* __restrict__ counts,
                                                   uint32_t* __restrict__ bMinU,
                                                   uint32_t* __restrict__ bMaxU) {
    int i = (int)(blockIdx.x * blockDim.x + threadIdx.x);
    if (i >= BATCH * NPTS) return;
    if (i < BATCH * NGRP * 3) { bMinU[i] = 0xFFFFFFFFu; bMaxU[i] = 0u; }
    vf4 v;
    v.x = xyz[(size_t)i * 3 + 0];
    v.y = xyz[(size_t)i * 3 + 1];
    v.z = xyz[(size_t)i * 3 + 2];
    v.w = 0.f;
    pc4[i] = v;
    int b = i >> 13;
    atomicAdd(&counts[b * NCELL + cell_of(v.x, v.y, v.z)], 1);
}

__global__ __launch_bounds__(1024) void scan_kernel(const int* __restrict__ counts,
                                                    int* __restrict__ cursor) {
    int b = (int)blockIdx.x, tid = (int)threadIdx.x;
    int lane = tid & 63, w = tid >> 6;
    __shared__ int wsum[16];
    int base = b * NCELL + tid * 4;
    int v0 = counts[base], v1 = counts[base + 1], v2 = counts[base + 2], v3 = counts[base + 3];
    int s = v0 + v1 + v2 + v3;
    int incl = s;
#pragma unroll
    for (int off = 1; off < 64; off <<= 1) {
        int o = __shfl_up(incl, off, 64);
        if (lane >= off) incl += o;
    }
    if (lane == 63) wsum[w] = incl;
    __syncthreads();
    if (tid == 0) {
        int acc = 0;
#pragma unroll
        for (int i = 0; i < 16; ++i) { int x = wsum[i]; wsum[i] = acc; acc += x; }
    }
    __syncthreads();
    int excl = incl - s + wsum[w];
    cursor[base]     = excl;
    cursor[base + 1] = excl + v0;
    cursor[base + 2] = excl + v0 + v1;
    cursor[base + 3] = excl + v0 + v1 + v2;
}

__global__ __launch_bounds__(256) void scatter_kernel(const vf4* __restrict__ pc4,
                                                      int* __restrict__ cursor,
                                                      vf4* __restrict__ sortedP,
                                                      uint32_t* __restrict__ bMinU,
                                                      uint32_t* __restrict__ bMaxU) {
    int i = (int)(blockIdx.x * blockDim.x + threadIdx.x);
    if (i >= BATCH * NPTS) return;
    vf4 v = pc4[i];
    int b = i >> 13, pi = i & (NPTS - 1);
    int c = cell_of(v.x, v.y, v.z);
    int pos = atomicAdd(&cursor[b * NCELL + c], 1);
    // group bbox accumulation: group id known from sorted position
    const int g = ((b << 7) + (pos >> 6)) * 3;
    atomicMin(&bMinU[g + 0], fenc(v.x));
    atomicMin(&bMinU[g + 1], fenc(v.y));
    atomicMin(&bMinU[g + 2], fenc(v.z));
    atomicMax(&bMaxU[g + 0], fenc(v.x));
    atomicMax(&bMaxU[g + 1], fenc(v.y));
    atomicMax(&bMaxU[g + 2], fenc(v.z));
    v.w = __uint_as_float((uint32_t)pi);
    sortedP[((size_t)b << 13) + pos] = v;
}

// ---------------------------------------------------------------------------
// Main refine: one wave per chain. FROZEN at round-8 logic (rotated lanes +
// collect fallback + XCD-aligned batches), interval-box bboxes from scatter.
// ---------------------------------------------------------------------------
__global__ __launch_bounds__(256)
__attribute__((amdgpu_waves_per_eu(2, 4)))
void refine_kernel(
    const vf4* __restrict__ pc4, const vf4* __restrict__ sortedP,
    const uint32_t* __restrict__ bMinU, const uint32_t* __restrict__ bMaxU,
    const float* __restrict__ center, const int* __restrict__ idx_in,
    float* __restrict__ pts_ws, int* __restrict__ idx_ws,
    int* __restrict__ grp_ws, int* __restrict__ conv_ws) {
    const int lane = (int)(threadIdx.x & 63);
    const int w = (int)(threadIdx.x >> 6);
    const int b = (int)(blockIdx.x & 7);                  // XCD-aligned batch
    const int s = (((int)blockIdx.x >> 3) << 2) + w;      // chain within batch
    const vf4* __restrict__ Porig = pc4 + ((size_t)b << 13);
    const vf4* __restrict__ Psort = sortedP + ((size_t)b << 13);

    __shared__ vf4 sMn[NGRP], sMx[NGRP];
    __shared__ vf4 nbh[4][KNN];
    __shared__ ull fbuf[4][FCAP];
    __shared__ int fcnt[4];

    // stage + decode the batch's 128 group bboxes into LDS
    {
        const int t = (int)threadIdx.x;
        if (t < NGRP) {
            const int gi = ((b << 7) + t) * 3;
            vf4 v;
            v.x = fdec(bMinU[gi + 0]); v.y = fdec(bMinU[gi + 1]);
            v.z = fdec(bMinU[gi + 2]); v.w = 0.f;
            sMn[t] = v;
        } else {
            const int tt = t - NGRP;
            const int gi = ((b << 7) + tt) * 3;
            vf4 v;
            v.x = fdec(bMaxU[gi + 0]); v.y = fdec(bMaxU[gi + 1]);
            v.z = fdec(bMaxU[gi + 2]); v.w = 0.f;
            sMx[tt] = v;
        }
    }
    __syncthreads();

    const size_t ch = ((size_t)b << 10) + (size_t)s;
    vf4 q;
    q.x = center[ch * 3 + 0];
    q.y = center[ch * 3 + 1];
    q.z = center[ch * 3 + 2];
    q.w = 0.f;
    int qidx = idx_in[ch];

    int conv = MAXIT;
    int my_ind = 0;
    vf4 myp = q;           // lanes<KNN: previous iteration's neighbor point
    bool warm = false;

    for (int it = 0;; ++it) {
        const float m0 = bbox_mind2_mm(q, sMn[lane], sMx[lane]);
        const float m1 = bbox_mind2_mm(q, sMn[64 + lane], sMx[64 + lane]);

        ull k0 = SENTKEY, k1 = SENTKEY, k2 = SENTKEY, k3 = SENTKEY;
        float th = __builtin_inff();
        ull sm0 = 0ull, sm1 = 0ull, am0 = 0ull, am1 = 0ull;
        float th0 = __builtin_inff();

        bool fastwarm = false;
        if (warm) {
            const float dw = (lane < KNN) ? d2_exact(q, myp) : 0.f;
            th0 = dw;
#pragma unroll
            for (int off = 32; off; off >>= 1)
                th0 = fmaxf(th0, xshflf(th0, off));
            sm0 = __ballot(m0 <= th0);
            sm1 = __ballot(m1 <= th0);
            const int nsel = __popcll(sm0) + __popcll(sm1);
            if (nsel <= 20) { fastwarm = true; am0 = sm0; am1 = sm1; }
        }

        if (!fastwarm) {
            // ---- sorted seed path (cold / fat-warm) ----
            sm0 = 0ull; sm1 = 0ull;
            uint32_t g0k = ((__float_as_uint(m0) >> 6) << 7) | (uint32_t)lane;
            uint32_t g1k = ((__float_as_uint(m1) >> 6) << 7) | (uint32_t)(64 + lane);
            sort128_u32(g0k, g1k, lane);
#pragma unroll
            for (int r = 0; r < NSEED; ++r) {
                const uint32_t nk = (r & 1)
                    ? (uint32_t)__shfl((int)g1k, r >> 1, 64)
                    : (uint32_t)__shfl((int)g0k, r >> 1, 64);
                const int gid = (int)(nk & 127u);
                if (gid < 64) sm0 |= 1ull << gid; else sm1 |= 1ull << (gid - 64);
                const vf4 p = Psort[(gid << 6) + ROTL(lane, gid)];
                const float d2 = d2_exact(q, p);
                if (d2 <= th)
                    insert_top4(((ull)__float_as_uint(d2) << 13) | __float_as_uint(p.w),
                                k0, k1, k2, k3, th);
            }
            // sound UB on 32nd-smallest: max of 32 distinct pairwise-min keys
            ull t = k0;
            {
                ull o = xshfl64(t, 32);
                t = o < t ? o : t;
            }
            const ull B = wave_max_u64(t);
            const float Bd = fminf(__uint_as_float((uint32_t)(B >> 13)), th0);
            am0 = __ballot(m0 <= Bd) & ~sm0;
            am1 = __ballot(m1 <= Bd) & ~sm1;
            sm0 |= am0; sm1 |= am1;
        }

        // ---- masked scan of remaining groups, 2-way unrolled ----
        {
            ull rem0 = am0, rem1 = am1;
            int ga = next_gid(rem0, rem1);
            while (ga >= 0) {
                const int gb2 = next_gid(rem0, rem1);
                const vf4 pa = Psort[(ga << 6) + ROTL(lane, ga)];
                vf4 pb;
                if (gb2 >= 0) pb = Psort[(gb2 << 6) + ROTL(lane, gb2)];
                const float da = d2_exact(q, pa);
                if (da <= th)
                    insert_top4(((ull)__float_as_uint(da) << 13) | __float_as_uint(pa.w),
                                k0, k1, k2, k3, th);
                if (gb2 >= 0) {
                    const float dbv = d2_exact(q, pb);
                    if (dbv <= th)
                        insert_top4(((ull)__float_as_uint(dbv) << 13) | __float_as_uint(pb.w),
                                    k0, k1, k2, k3, th);
                }
                ga = next_gid(rem0, rem1);
            }
        }
        const ull prek3 = k3;

        // ---- wave bitonic sort of 256 candidates (sentinel-padded) ----
        const bool odd = (lane & 1) != 0;
        ull a0 = odd ? k3 : k0;
        ull a1 = odd ? k2 : k1;
        ull a2 = odd ? k1 : k2;
        ull a3 = odd ? k0 : k3;
#pragma unroll
        for (int kk = 8; kk <= 256; kk <<= 1) {
            const bool up = (lane & (kk >> 2)) == 0;
#pragma unroll
            for (int d = kk >> 1; d >= 4; d >>= 1) {
                const int xl = d >> 2;
                const bool keepmin = (up == ((lane & xl) == 0));
                a0 = cx(a0, xl, keepmin);
                a1 = cx(a1, xl, keepmin);
                a2 = cx(a2, xl, keepmin);
                a3 = cx(a3, xl, keepmin);
            }
            cswap(a0, a2, up); cswap(a1, a3, up);
            cswap(a0, a1, up); cswap(a2, a3, up);
        }
        // rank r lives at lane r>>2, reg r&3; tau = rank-31 key
        const ull tau = (ull)__shfl((unsigned long long)a3, 7, 64);
        const ull bad = __ballot(prek3 < tau);
        if (bad != 0ull) {
            const int mi = collect_topk(Psort, q, lane, sm0, sm1, tau,
                                        fbuf[w], &fcnt[w]);
            my_ind = (mi >= 0) ? mi : serial_topk_masked(Psort, q, lane, sm0, sm1);
        } else {
            const int src = lane >> 2;
            const uint32_t lo0 = (uint32_t)__shfl((int)(uint32_t)a0, src, 64);
            const uint32_t lo1 = (uint32_t)__shfl((int)(uint32_t)a1, src, 64);
            const uint32_t lo2 = (uint32_t)__shfl((int)(uint32_t)a2, src, 64);
            const uint32_t lo3 = (uint32_t)__shfl((int)(uint32_t)a3, src, 64);
            const int sel = lane & 3;
            uint32_t lo = (sel == 0) ? lo0 : (sel == 1) ? lo1 : (sel == 2) ? lo2 : lo3;
            my_ind = (int)(lo & 0x1FFFu);
        }

        if (it == MAXIT) break;  // final step's ind recorded; conv stays MAXIT

        // ---- centroid: stage 32 ordered neighbors to LDS, sequential fold ----
        myp = q;
        if (lane < KNN) {
            myp = Porig[my_ind];
            nbh[w][lane] = myp;
        }
        __asm__ volatile("s_waitcnt lgkmcnt(0)" ::: "memory");
        float sx = 0.f, sy = 0.f, sz = 0.f;
#pragma unroll
        for (int j = 0; j < KNN; ++j) {
            vf4 pj = nbh[w][j];
            sx = __fadd_rn(sx, pj.x);
            sy = __fadd_rn(sy, pj.y);
            sz = __fadd_rn(sz, pj.z);
        }
        const float gx = __fmul_rn(sx, 0.03125f);
        const float gy = __fmul_rn(sy, 0.03125f);
        const float gz = __fmul_rn(sz, 0.03125f);

        // ---- per-neighbor distance to centroid (post-sqrt ordering) ----
        float dj = __builtin_inff();
        if (lane < KNN) {
            const float dx = __fsub_rn(myp.x, gx);
            const float dy = __fsub_rn(myp.y, gy);
            const float dz = __fsub_rn(myp.z, gz);
            dj = sqrtf(__fadd_rn(__fadd_rn(__fmul_rn(dx, dx), __fmul_rn(dy, dy)),
                                 __fmul_rn(dz, dz)));
        }
        const uint32_t db = __float_as_uint(dj);  // nonneg: bit order == fp order
        const uint32_t d0 = (uint32_t)__shfl((int)db, 0, 64);
        const ull bal = __ballot(db < d0);
        if (__popcll(bal) <= TOPC - 1) { conv = it; break; }

        // move target: lexicographic argmin of (dist, j)
        uint32_t m = db;
#pragma unroll
        for (int off = 32; off; off >>= 1) {
            uint32_t o = xshfl32(m, off);
            m = o < m ? o : m;
        }
        const ull balm = __ballot(db == m);
        const int jm = __ffsll((unsigned long long)balm) - 1;
        qidx = __shfl(my_ind, jm, 64);
        q.x = __shfl(myp.x, jm, 64);
        q.y = __shfl(myp.y, jm, 64);
        q.z = __shfl(myp.z, jm, 64);
        q.w = 0.f;
        warm = true;
    }

    if (lane < KNN) grp_ws[ch * KNN + lane] = my_ind;
    if (lane == 0) {
        pts_ws[ch * 3 + 0] = q.x;
        pts_ws[ch * 3 + 1] = q.y;
        pts_ws[ch * 3 + 2] = q.z;
        idx_ws[ch] = qidx;
        conv_ws[ch] = conv;
    }
}

// ---------------------------------------------------------------------------
// Order: stable rank by (conv, s) via 17-bin counting (round-9 verified)
// ---------------------------------------------------------------------------
__global__ __launch_bounds__(1024) void order_kernel(
    const float* __restrict__ pts_ws, const int* __restrict__ idx_ws,
    const int* __restrict__ grp_ws, const int* __restrict__ conv_ws,
    float* __restrict__ out) {
    const int b = (int)blockIdx.x;
    const int s = (int)threadIdx.x;
    const int w = s >> 6, l = s & 63;
    __shared__ int wavecnt[16][MAXIT + 1];
    __shared__ int binbase[MAXIT + 1];
    const size_t ch = (size_t)b * SCH + s;
    const int c = conv_ws[ch];
    int rw = 0;
#pragma unroll
    for (int v = 0; v <= MAXIT; ++v) {
        ull bal = __ballot(c == v);
        if (l == 0) wavecnt[w][v] = (int)__popcll(bal);
        if (c == v) rw = (int)__popcll(bal & ((1ull << l) - 1ull));
    }
    __syncthreads();
    if (s == 0) {
        int acc = 0;
        for (int v = 0; v <= MAXIT; ++v) {
            int t = 0;
            for (int w2 = 0; w2 < 16; ++w2) t += wavecnt[w2][v];
            binbase[v] = acc;
            acc += t;
        }
    }
    __syncthreads();
    int pos = binbase[c] + rw;
    for (int w2 = 0; w2 < w; ++w2) pos += wavecnt[w2][c];

    float* __restrict__ C  = out;                              // (B,S,3)
    float* __restrict__ I1 = out + (size_t)BATCH * SCH * 3;    // (B,S)
    float* __restrict__ I2 = I1 + (size_t)BATCH * SCH;         // (B,S,K)
    const size_t o = (size_t)b * SCH + pos;
    C[o * 3 + 0] = pts_ws[ch * 3 + 0];
    C[o * 3 + 1] = pts_ws[ch * 3 + 1];
    C[o * 3 + 2] = pts_ws[ch * 3 + 2];
    I1[o] = (float)idx_ws[ch];
#pragma unroll
    for (int k = 0; k < KNN; ++k) I2[o * KNN + k] = (float)grp_ws[ch * KNN + k];
}

extern "C" void kernel_launch(void* const* d_in, const int* in_sizes, int n_in,
                              void* d_out, int out_size, void* d_ws, size_t ws_size,
                              hipStream_t stream) {
    const float* xyz    = (const float*)d_in[0];  // (8,8192,3) f32
    const float* center = (const float*)d_in[1];  // (8,1024,3) f32
    const int*   idx_in = (const int*)d_in[2];    // (8,1024)   i32
    float* out = (float*)d_out;

    // workspace layout (~3.5 MB)
    char* wp = (char*)d_ws;
    vf4* pc4     = (vf4*)wp;  wp += (size_t)BATCH * NPTS * sizeof(vf4);   // 1 MB
    vf4* sortedP = (vf4*)wp;  wp += (size_t)BATCH * NPTS * sizeof(vf4);   // 1 MB
    uint32_t* bMinU = (uint32_t*)wp; wp += (size_t)BATCH * NGRP * 3 * 4;  // 12 KB
    uint32_t* bMaxU = (uint32_t*)wp; wp += (size_t)BATCH * NGRP * 3 * 4;  // 12 KB
    int* counts  = (int*)wp;  wp += (size_t)BATCH * NCELL * 4;            // 128 KB
    int* cursor  = (int*)wp;  wp += (size_t)BATCH * NCELL * 4;            // 128 KB
    float* pts_ws = (float*)wp; wp += (size_t)BATCH * SCH * 3 * 4;
    int*   idx_ws = (int*)wp;   wp += (size_t)BATCH * SCH * 4;
    int*   grp_ws = (int*)wp;   wp += (size_t)BATCH * SCH * KNN * 4;      // 1 MB
    int*   conv_ws = (int*)wp;

    hipMemsetAsync(counts, 0, (size_t)BATCH * NCELL * 4, stream);
    prep_kernel<<<(BATCH * NPTS + 255) / 256, 256, 0, stream>>>(
        xyz, pc4, counts, bMinU, bMaxU);
    scan_kernel<<<BATCH, 1024, 0, stream>>>(counts, cursor);
    scatter_kernel<<<(BATCH * NPTS + 255) / 256, 256, 0, stream>>>(
        pc4, cursor, sortedP, bMinU, bMaxU);

    const int chains = BATCH * SCH;                 // 8192 waves, 1 per chain
    refine_kernel<<<chains * 64 / 256, 256, 0, stream>>>(
        pc4, sortedP, bMinU, bMaxU, center, idx_in,
        pts_ws, idx_ws, grp_ws, conv_ws);
    order_kernel<<<BATCH, SCH, 0, stream>>>(pts_ws, idx_ws, grp_ws, conv_ws, out);
}

// Round 13
// 180.646 us; speedup vs baseline: 1.3195x; 1.0545x over previous
//
#include <hip/hip_runtime.h>
#include <stdint.h>

#define BATCH   8
#define NPTS    8192
#define SCH     1024
#define KNN     32
#define TOPC    5
#define MAXIT   16
#define NCELL   4096     // 16^3 morton cells
#define NGRP    128      // groups of 64 per batch
#define NSEED   6        // cold-path seed groups scanned in mind2 order
#define FCAP    128      // collect-fallback LDS capacity (keys <= tau)

typedef unsigned long long ull;
typedef float vf2 __attribute__((ext_vector_type(2)));
typedef float vf4 __attribute__((ext_vector_type(4)));

// sentinel: unpacks to +inf d2, never enters top-32
#define SENTKEY ((((ull)0x7F800000u) << 13) | 0x1FFFull)

// rotated intra-group lane assignment (round-8 proven: fallback ~8% -> ~1-2%)
#define ROTL(lane, g) (((lane) + (g) * 17) & 63)

// ---------------------------------------------------------------------------
// Cross-lane xor exchange: xor-1/xor-2 via DPP quad_perm (VALU pipe).
// ---------------------------------------------------------------------------
__device__ __forceinline__ uint32_t xshfl32(uint32_t v, int xl) {
    if (xl == 1)
        return (uint32_t)__builtin_amdgcn_update_dpp((int)v, (int)v, 0xB1, 0xF, 0xF, true);
    if (xl == 2)
        return (uint32_t)__builtin_amdgcn_update_dpp((int)v, (int)v, 0x4E, 0xF, 0xF, true);
    return (uint32_t)__shfl_xor((int)v, xl, 64);
}
__device__ __forceinline__ ull xshfl64(ull v, int xl) {
    uint32_t lo = xshfl32((uint32_t)v, xl);
    uint32_t hi = xshfl32((uint32_t)(v >> 32), xl);
    return ((ull)hi << 32) | lo;
}
__device__ __forceinline__ float xshflf(float v, int xl) {
    return __uint_as_float(xshfl32(__float_as_uint(v), xl));
}

// ---------------------------------------------------------------------------
// Exact d2: separate mul/add roundings (no FMA), order ((dx2+dy2)+dz2) = numpy.
// ---------------------------------------------------------------------------
__device__ __forceinline__ float d2_exact(vf4 q, vf4 p) {
#pragma clang fp contract(off)
    vf2 d = q.xy - p.xy;
    vf2 s = d * d;
    float dz = q.z - p.z;
    float sz = dz * dz;
    return (s.x + s.y) + sz;
}

__device__ __forceinline__ void insert_top4(ull key, ull& k0, ull& k1, ull& k2,
                                            ull& k3, float& th) {
    if (key < k3) {
        k3 = key;
        { bool c = k3 < k2; ull mn = c ? k3 : k2, mx = c ? k2 : k3; k2 = mn; k3 = mx; }
        { bool c = k2 < k1; ull mn = c ? k2 : k1, mx = c ? k1 : k2; k1 = mn; k2 = mx; }
        { bool c = k1 < k0; ull mn = c ? k1 : k0, mx = c ? k0 : k1; k0 = mn; k1 = mx; }
        th = __uint_as_float((uint32_t)(k3 >> 13));
    }
}

__device__ __forceinline__ ull wave_min_u64(ull k) {
#pragma unroll
    for (int off = 32; off; off >>= 1) {
        ull o = xshfl64(k, off);
        k = o < k ? o : k;
    }
    return k;
}
__device__ __forceinline__ ull wave_max_u64(ull k) {
#pragma unroll
    for (int off = 32; off; off >>= 1) {
        ull o = xshfl64(k, off);
        k = o > k ? o : k;
    }
    return k;
}

// conservative (under-estimated) squared min distance from q to group bbox
__device__ __forceinline__ float bbox_mind2(vf4 q, vf4 c, vf4 h) {
    float dx = fmaxf(fabsf(q.x - c.x) - h.x, 0.f);
    float dy = fmaxf(fabsf(q.y - c.y) - h.y, 0.f);
    float dz = fmaxf(fabsf(q.z - c.z) - h.z, 0.f);
    return (dx * dx + dy * dy + dz * dz) * 0.9999f;
}

// bitonic helpers (64-bit)
__device__ __forceinline__ ull cx(ull v, int xl, bool keepmin) {
    ull o = xshfl64(v, xl);
    return ((v < o) == keepmin) ? v : o;
}
__device__ __forceinline__ void cswap(ull& a, ull& b, bool up) {
    bool lt = a < b;
    ull mn = lt ? a : b, mx = lt ? b : a;
    a = up ? mn : mx;
    b = up ? mx : mn;
}

// bitonic helpers (32-bit)
__device__ __forceinline__ uint32_t cx32(uint32_t v, int xl, bool keepmin) {
    uint32_t o = xshfl32(v, xl);
    return ((v < o) == keepmin) ? v : o;
}
__device__ __forceinline__ void cswap32(uint32_t& a, uint32_t& b, bool up) {
    uint32_t mn = a < b ? a : b, mx = a < b ? b : a;
    a = up ? mn : mx;
    b = up ? mx : mn;
}

// full bitonic sort of 128 u32 keys, 2 regs/lane (element = 2*lane+reg).
// After: ascending; rank r lives at lane r>>1, reg r&1.
__device__ __forceinline__ void sort128_u32(uint32_t& s0, uint32_t& s1, int lane) {
    cswap32(s0, s1, true);
    if (lane & 1) { uint32_t t = s0; s0 = s1; s1 = t; }
#pragma unroll
    for (int kk = 4; kk <= 128; kk <<= 1) {
        const bool up = (lane & (kk >> 1)) == 0;
#pragma unroll
        for (int d = kk >> 1; d >= 2; d >>= 1) {
            const int xl = d >> 1;
            const bool keepmin = (up == ((lane & xl) == 0));
            s0 = cx32(s0, xl, keepmin);
            s1 = cx32(s1, xl, keepmin);
        }
        cswap32(s0, s1, up);
    }
}

// same network, 64-bit keys (collect-fallback sort)
__device__ __forceinline__ void sort128_u64(ull& s0, ull& s1, int lane) {
    cswap(s0, s1, true);
    if (lane & 1) { ull t = s0; s0 = s1; s1 = t; }
#pragma unroll
    for (int kk = 4; kk <= 128; kk <<= 1) {
        const bool up = (lane & (kk >> 1)) == 0;
#pragma unroll
        for (int d = kk >> 1; d >= 2; d >>= 1) {
            const int xl = d >> 1;
            const bool keepmin = (up == ((lane & xl) == 0));
            s0 = cx(s0, xl, keepmin);
            s1 = cx(s1, xl, keepmin);
        }
        cswap(s0, s1, up);
    }
}

// pop next selected group id from the wave-uniform pair of masks
__device__ __forceinline__ int next_gid(ull& r0, ull& r1) {
    if (r0) { int g = __ffsll((unsigned long long)r0) - 1; r0 &= r0 - 1; return g; }
    if (r1) { int g = __ffsll((unsigned long long)r1) - 1; r1 &= r1 - 1; return 64 + g; }
    return -1;
}

// morton cell id from point (16^3 over [-4,4], clamped)
__device__ __forceinline__ int cell_of(float x, float y, float z) {
    int cxi = min(15, max(0, (int)floorf((x + 4.0f) * 2.0f)));
    int cyi = min(15, max(0, (int)floorf((y + 4.0f) * 2.0f)));
    int czi = min(15, max(0, (int)floorf((z + 4.0f) * 2.0f)));
    uint32_t sx = (cxi & 1) | ((cxi & 2) << 2) | ((cxi & 4) << 4) | ((cxi & 8) << 6);
    uint32_t sy = (cyi & 1) | ((cyi & 2) << 2) | ((cyi & 4) << 4) | ((cyi & 8) << 6);
    uint32_t sz = (czi & 1) | ((czi & 2) << 2) | ((czi & 4) << 4) | ((czi & 8) << 6);
    return (int)(sx | (sy << 1) | (sz << 2));
}

// ---------------------------------------------------------------------------
// Backstop fallback (ultra-rare): exact serial extraction with refills.
// ---------------------------------------------------------------------------
__device__ __attribute__((noinline)) int serial_topk_masked(
    const vf4* __restrict__ Psort, vf4 q, int lane, ull sm0, ull sm1) {
    ull k0 = SENTKEY, k1 = SENTKEY, k2 = SENTKEY, k3 = SENTKEY;
    int s0 = 0, s1 = 0, s2 = 0, s3 = 0;
    float th = __builtin_inff();
    for (int gid = 0; gid < NGRP; ++gid) {
        bool sel = (gid < 64) ? ((sm0 >> gid) & 1ull) : ((sm1 >> (gid - 64)) & 1ull);
        if (!sel) continue;
        vf4 p = Psort[(gid << 6) + lane];
        float d2 = d2_exact(q, p);
        uint32_t oi = __float_as_uint(p.w);
        ull key = ((ull)__float_as_uint(d2) << 13) | oi;
        if (d2 <= th && key < k3) {
            k3 = key; s3 = gid;
            if (k3 < k2) { ull t = k2; k2 = k3; k3 = t; int ts = s2; s2 = s3; s3 = ts; }
            if (k2 < k1) { ull t = k1; k1 = k2; k2 = t; int ts = s1; s1 = s2; s2 = ts; }
            if (k1 < k0) { ull t = k0; k0 = k1; k1 = t; int ts = s0; s0 = s1; s1 = ts; }
            th = __uint_as_float((uint32_t)(k3 >> 13));
        }
    }
    ull em0 = 0ull, em1 = 0ull;
    int cnt = 4, my_ind = 0;
    for (int r = 0; r < KNN; ++r) {
        ull gmin = wave_min_u64(k0);
        int widx = (int)(gmin & 0x1FFFull);
        if (lane == r) my_ind = widx;
        if (k0 == gmin) {
            int g = s0;
            if (g < 64) em0 |= 1ull << g; else em1 |= 1ull << (g - 64);
            k0 = k1; k1 = k2; k2 = k3; k3 = SENTKEY;
            s0 = s1; s1 = s2; s2 = s3;
            if (--cnt == 0) {
                k0 = k1 = k2 = k3 = SENTKEY;
                float th2 = __builtin_inff();
                for (int gid = 0; gid < NGRP; ++gid) {
                    bool sel = (gid < 64) ? ((sm0 >> gid) & 1ull)
                                          : ((sm1 >> (gid - 64)) & 1ull);
                    bool ex = (gid < 64) ? ((em0 >> gid) & 1ull)
                                         : ((em1 >> (gid - 64)) & 1ull);
                    if (!sel || ex) continue;
                    vf4 p = Psort[(gid << 6) + lane];
                    float d2 = d2_exact(q, p);
                    uint32_t oi = __float_as_uint(p.w);
                    ull key = ((ull)__float_as_uint(d2) << 13) | oi;
                    if (d2 <= th2 && key < k3) {
                        k3 = key; s3 = gid;
                        if (k3 < k2) { ull t = k2; k2 = k3; k3 = t; int ts = s2; s2 = s3; s3 = ts; }
                        if (k2 < k1) { ull t = k1; k1 = k2; k2 = t; int ts = s1; s1 = s2; s2 = ts; }
                        if (k1 < k0) { ull t = k0; k0 = k1; k1 = t; int ts = s0; s0 = s1; s1 = ts; }
                        th2 = __uint_as_float((uint32_t)(k3 >> 13));
                    }
                }
                cnt = 4;
            }
        }
    }
    return my_ind;
}

// ---------------------------------------------------------------------------
// Cheap exact fallback (round-8 proven): collect all keys <= tau, sort 128.
// ---------------------------------------------------------------------------
__device__ int collect_topk(const vf4* __restrict__ Psort, vf4 q, int lane,
                            ull sm0, ull sm1, ull tau,
                            ull* buf, int* cnt) {
    if (lane == 0) *cnt = 0;
    __asm__ volatile("s_waitcnt lgkmcnt(0)" ::: "memory");
    ull r0 = sm0, r1 = sm1;
    int g = next_gid(r0, r1);
    while (g >= 0) {
        vf4 p = Psort[(g << 6) + lane];
        float d2 = d2_exact(q, p);
        ull key = ((ull)__float_as_uint(d2) << 13) | __float_as_uint(p.w);
        if (key <= tau) {
            int pos = atomicAdd(cnt, 1);
            if (pos < FCAP) buf[pos] = key;
        }
        g = next_gid(r0, r1);
    }
    __asm__ volatile("s_waitcnt lgkmcnt(0)" ::: "memory");
    const int M = *cnt;          // wave-uniform
    if (M > FCAP) return -1;
    ull s0 = (2 * lane + 0 < M) ? buf[2 * lane + 0] : SENTKEY;
    ull s1 = (2 * lane + 1 < M) ? buf[2 * lane + 1] : SENTKEY;
    sort128_u64(s0, s1, lane);
    const int src = lane >> 1;
    const uint32_t e0 = (uint32_t)__shfl((int)(uint32_t)s0, src, 64);
    const uint32_t e1 = (uint32_t)__shfl((int)(uint32_t)s1, src, 64);
    return (int)(((lane & 1) ? e1 : e0) & 0x1FFFu);
}

// ---------------------------------------------------------------------------
// Build phase: parallel multi-kernel (round-7/9 proven). One-block-per-batch
// fusion refuted twice (rounds 5/6, 8); fused cross-block ordering refuted
// (round 11: device fences force L2 writebacks on non-coherent XCD L2s).
// ---------------------------------------------------------------------------
__global__ __launch_bounds__(256) void prep_kernel(const float* __restrict__ xyz,
                                                   vf4* __restrict__ pc4,
                                                   int* __restrict__ counts) {
    int i = (int)(blockIdx.x * blockDim.x + threadIdx.x);
    if (i >= BATCH * NPTS) return;
    vf4 v;
    v.x = xyz[(size_t)i * 3 + 0];
    v.y = xyz[(size_t)i * 3 + 1];
    v.z = xyz[(size_t)i * 3 + 2];
    v.w = 0.f;
    pc4[i] = v;
    int b = i >> 13;
    atomicAdd(&counts[b * NCELL + cell_of(v.x, v.y, v.z)], 1);
}

__global__ __launch_bounds__(1024) void scan_kernel(const int* __restrict__ counts,
                                                    int* __restrict__ cursor) {
    int b = (int)blockIdx.x, tid = (int)threadIdx.x;
    int lane = tid & 63, w = tid >> 6;
    __shared__ int wsum[16];
    int base = b * NCELL + tid * 4;
    int v0 = counts[base], v1 = counts[base + 1], v2 = counts[base + 2], v3 = counts[base + 3];
    int s = v0 + v1 + v2 + v3;
    int incl = s;
#pragma unroll
    for (int off = 1; off < 64; off <<= 1) {
        int o = __shfl_up(incl, off, 64);
        if (lane >= off) incl += o;
    }
    if (lane == 63) wsum[w] = incl;
    __syncthreads();
    if (tid == 0) {
        int acc = 0;
#pragma unroll
        for (int i = 0; i < 16; ++i) { int x = wsum[i]; wsum[i] = acc; acc += x; }
    }
    __syncthreads();
    int excl = incl - s + wsum[w];
    cursor[base]     = excl;
    cursor[base + 1] = excl + v0;
    cursor[base + 2] = excl + v0 + v1;
    cursor[base + 3] = excl + v0 + v1 + v2;
}

__global__ __launch_bounds__(256) void scatter_kernel(const vf4* __restrict__ pc4,
                                                      int* __restrict__ cursor,
                                                      vf4* __restrict__ sortedP) {
    int i = (int)(blockIdx.x * blockDim.x + threadIdx.x);
    if (i >= BATCH * NPTS) return;
    vf4 v = pc4[i];
    int b = i >> 13, pi = i & (NPTS - 1);
    int c = cell_of(v.x, v.y, v.z);
    int pos = atomicAdd(&cursor[b * NCELL + c], 1);
    v.w = __uint_as_float((uint32_t)pi);
    sortedP[((size_t)b << 13) + pos] = v;
}

__global__ __launch_bounds__(256) void bbox_kernel(const vf4* __restrict__ sortedP,
                                                   vf4* __restrict__ bC,
                                                   vf4* __restrict__ bH) {
    int g = (int)((blockIdx.x * blockDim.x + threadIdx.x) >> 6);  // 0..B*NGRP-1
    int lane = (int)(threadIdx.x & 63);
    vf4 p = sortedP[((size_t)g << 6) + lane];
    float mnx = p.x, mxx = p.x, mny = p.y, mxy = p.y, mnz = p.z, mxz = p.z;
#pragma unroll
    for (int off = 32; off; off >>= 1) {
        mnx = fminf(mnx, xshflf(mnx, off));
        mxx = fmaxf(mxx, xshflf(mxx, off));
        mny = fminf(mny, xshflf(mny, off));
        mxy = fmaxf(mxy, xshflf(mxy, off));
        mnz = fminf(mnz, xshflf(mnz, off));
        mxz = fmaxf(mxz, xshflf(mxz, off));
    }
    if (lane == 0) {
        vf4 c, h;
        c.x = (mnx + mxx) * 0.5f; c.y = (mny + mxy) * 0.5f; c.z = (mnz + mxz) * 0.5f; c.w = 0.f;
        h.x = (mxx - mnx) * 0.5f; h.y = (mxy - mny) * 0.5f; h.z = (mxz - mnz) * 0.5f; h.w = 0.f;
        bC[g] = c;
        bH[g] = h;
    }
}

// ---------------------------------------------------------------------------
// Main refine: one wave per chain. FROZEN at round-8 (rotated lanes +
// collect fallback + XCD-aligned batches). Best-measured config (round 9).
// ---------------------------------------------------------------------------
__global__ __launch_bounds__(256)
__attribute__((amdgpu_waves_per_eu(2, 4)))
void refine_kernel(
    const vf4* __restrict__ pc4, const vf4* __restrict__ sortedP,
    const vf4* __restrict__ bC, const vf4* __restrict__ bH,
    const float* __restrict__ center, const int* __restrict__ idx_in,
    float* __restrict__ pts_ws, int* __restrict__ idx_ws,
    int* __restrict__ grp_ws, int* __restrict__ conv_ws) {
    const int lane = (int)(threadIdx.x & 63);
    const int w = (int)(threadIdx.x >> 6);
    const int b = (int)(blockIdx.x & 7);                  // XCD-aligned batch
    const int s = (((int)blockIdx.x >> 3) << 2) + w;      // chain within batch
    const vf4* __restrict__ Porig = pc4 + ((size_t)b << 13);
    const vf4* __restrict__ Psort = sortedP + ((size_t)b << 13);

    __shared__ vf4 sbC[NGRP], sbH[NGRP];
    __shared__ vf4 nbh[4][KNN];
    __shared__ ull fbuf[4][FCAP];
    __shared__ int fcnt[4];

    // stage the batch's 128 group bboxes into LDS (block-uniform batch)
    {
        const int t = (int)threadIdx.x;
        if (t < NGRP) sbC[t] = bC[(b << 7) + t];
        else          sbH[t - NGRP] = bH[(b << 7) + (t - NGRP)];
    }
    __syncthreads();

    const size_t ch = ((size_t)b << 10) + (size_t)s;
    vf4 q;
    q.x = center[ch * 3 + 0];
    q.y = center[ch * 3 + 1];
    q.z = center[ch * 3 + 2];
    q.w = 0.f;
    int qidx = idx_in[ch];

    int conv = MAXIT;
    int my_ind = 0;
    vf4 myp = q;           // lanes<KNN: previous iteration's neighbor point
    bool warm = false;

    for (int it = 0;; ++it) {
        const vf4 c0 = sbC[lane],      h0 = sbH[lane];
        const vf4 c1 = sbC[64 + lane], h1 = sbH[64 + lane];
        const float m0 = bbox_mind2(q, c0, h0);
        const float m1 = bbox_mind2(q, c1, h1);

        ull k0 = SENTKEY, k1 = SENTKEY, k2 = SENTKEY, k3 = SENTKEY;
        float th = __builtin_inff();
        ull sm0 = 0ull, sm1 = 0ull, am0 = 0ull, am1 = 0ull;
        float th0 = __builtin_inff();

        bool fastwarm = false;
        if (warm) {
            // tight bound: q moved to one of its previous top-32, so the
            // previous neighbors at the new q bound the new 32nd distance
            const float dw = (lane < KNN) ? d2_exact(q, myp) : 0.f;
            th0 = dw;
#pragma unroll
            for (int off = 32; off; off >>= 1)
                th0 = fmaxf(th0, xshflf(th0, off));
            sm0 = __ballot(m0 <= th0);
            sm1 = __ballot(m1 <= th0);
            const int nsel = __popcll(sm0) + __popcll(sm1);
            if (nsel <= 20) { fastwarm = true; am0 = sm0; am1 = sm1; }
        }

        if (!fastwarm) {
            // ---- sorted seed path (cold / fat-warm) ----
            sm0 = 0ull; sm1 = 0ull;
            uint32_t g0k = ((__float_as_uint(m0) >> 6) << 7) | (uint32_t)lane;
            uint32_t g1k = ((__float_as_uint(m1) >> 6) << 7) | (uint32_t)(64 + lane);
            sort128_u32(g0k, g1k, lane);
            // scan the NSEED nearest groups in (truncated) mind2 order
#pragma unroll
            for (int r = 0; r < NSEED; ++r) {
                const uint32_t nk = (r & 1)
                    ? (uint32_t)__shfl((int)g1k, r >> 1, 64)
                    : (uint32_t)__shfl((int)g0k, r >> 1, 64);
                const int gid = (int)(nk & 127u);
                if (gid < 64) sm0 |= 1ull << gid; else sm1 |= 1ull << (gid - 64);
                const vf4 p = Psort[(gid << 6) + ROTL(lane, gid)];
                const float d2 = d2_exact(q, p);
                if (d2 <= th)
                    insert_top4(((ull)__float_as_uint(d2) << 13) | __float_as_uint(p.w),
                                k0, k1, k2, k3, th);
            }
            // sound UB on 32nd-smallest: max of 32 distinct pairwise-min keys
            ull t = k0;
            {
                ull o = xshfl64(t, 32);
                t = o < t ? o : t;
            }
            const ull B = wave_max_u64(t);
            const float Bd = fminf(__uint_as_float((uint32_t)(B >> 13)), th0);
            am0 = __ballot(m0 <= Bd) & ~sm0;
            am1 = __ballot(m1 <= Bd) & ~sm1;
            sm0 |= am0; sm1 |= am1;
        }

        // ---- masked scan of remaining groups, 2-way unrolled ----
        {
            ull rem0 = am0, rem1 = am1;
            int ga = next_gid(rem0, rem1);
            while (ga >= 0) {
                const int gb2 = next_gid(rem0, rem1);
                const vf4 pa = Psort[(ga << 6) + ROTL(lane, ga)];
                vf4 pb;
                if (gb2 >= 0) pb = Psort[(gb2 << 6) + ROTL(lane, gb2)];
                const float da = d2_exact(q, pa);
                if (da <= th)
                    insert_top4(((ull)__float_as_uint(da) << 13) | __float_as_uint(pa.w),
                                k0, k1, k2, k3, th);
                if (gb2 >= 0) {
                    const float dbv = d2_exact(q, pb);
                    if (dbv <= th)
                        insert_top4(((ull)__float_as_uint(dbv) << 13) | __float_as_uint(pb.w),
                                    k0, k1, k2, k3, th);
                }
                ga = next_gid(rem0, rem1);
            }
        }
        const ull prek3 = k3;

        // ---- wave bitonic sort of 256 candidates (sentinel-padded) ----
        const bool odd = (lane & 1) != 0;
        ull a0 = odd ? k3 : k0;
        ull a1 = odd ? k2 : k1;
        ull a2 = odd ? k1 : k2;
        ull a3 = odd ? k0 : k3;
#pragma unroll
        for (int kk = 8; kk <= 256; kk <<= 1) {
            const bool up = (lane & (kk >> 2)) == 0;
#pragma unroll
            for (int d = kk >> 1; d >= 4; d >>= 1) {
                const int xl = d >> 2;
                const bool keepmin = (up == ((lane & xl) == 0));
                a0 = cx(a0, xl, keepmin);
                a1 = cx(a1, xl, keepmin);
                a2 = cx(a2, xl, keepmin);
                a3 = cx(a3, xl, keepmin);
            }
            cswap(a0, a2, up); cswap(a1, a3, up);
            cswap(a0, a1, up); cswap(a2, a3, up);
        }
        // rank r lives at lane r>>2, reg r&3; tau = rank-31 key
        const ull tau = (ull)__shfl((unsigned long long)a3, 7, 64);
        const ull bad = __ballot(prek3 < tau);
        if (bad != 0ull) {
            const int mi = collect_topk(Psort, q, lane, sm0, sm1, tau,
                                        fbuf[w], &fcnt[w]);
            my_ind = (mi >= 0) ? mi : serial_topk_masked(Psort, q, lane, sm0, sm1);
        } else {
            const int src = lane >> 2;
            const uint32_t lo0 = (uint32_t)__shfl((int)(uint32_t)a0, src, 64);
            const uint32_t lo1 = (uint32_t)__shfl((int)(uint32_t)a1, src, 64);
            const uint32_t lo2 = (uint32_t)__shfl((int)(uint32_t)a2, src, 64);
            const uint32_t lo3 = (uint32_t)__shfl((int)(uint32_t)a3, src, 64);
            const int sel = lane & 3;
            uint32_t lo = (sel == 0) ? lo0 : (sel == 1) ? lo1 : (sel == 2) ? lo2 : lo3;
            my_ind = (int)(lo & 0x1FFFu);
        }

        if (it == MAXIT) break;  // final step's ind recorded; conv stays MAXIT

        // ---- centroid: stage 32 ordered neighbors to LDS, sequential fold ----
        myp = q;
        if (lane < KNN) {
            myp = Porig[my_ind];
            nbh[w][lane] = myp;
        }
        __asm__ volatile("s_waitcnt lgkmcnt(0)" ::: "memory");
        float sx = 0.f, sy = 0.f, sz = 0.f;
#pragma unroll
        for (int j = 0; j < KNN; ++j) {
            vf4 pj = nbh[w][j];
            sx = __fadd_rn(sx, pj.x);
            sy = __fadd_rn(sy, pj.y);
            sz = __fadd_rn(sz, pj.z);
        }
        const float gx = __fmul_rn(sx, 0.03125f);
        const float gy = __fmul_rn(sy, 0.03125f);
        const float gz = __fmul_rn(sz, 0.03125f);

        // ---- per-neighbor distance to centroid (post-sqrt ordering) ----
        float dj = __builtin_inff();
        if (lane < KNN) {
            const float dx = __fsub_rn(myp.x, gx);
            const float dy = __fsub_rn(myp.y, gy);
            const float dz = __fsub_rn(myp.z, gz);
            dj = sqrtf(__fadd_rn(__fadd_rn(__fmul_rn(dx, dx), __fmul_rn(dy, dy)),
                                 __fmul_rn(dz, dz)));
        }
        const uint32_t db = __float_as_uint(dj);  // nonneg: bit order == fp order
        const uint32_t d0 = (uint32_t)__shfl((int)db, 0, 64);
        const ull bal = __ballot(db < d0);
        if (__popcll(bal) <= TOPC - 1) { conv = it; break; }

        // move target: lexicographic argmin of (dist, j)
        uint32_t m = db;
#pragma unroll
        for (int off = 32; off; off >>= 1) {
            uint32_t o = xshfl32(m, off);
            m = o < m ? o : m;
        }
        const ull balm = __ballot(db == m);
        const int jm = __ffsll((unsigned long long)balm) - 1;
        // new q = lane jm's neighbor point (coords already in myp registers)
        qidx = __shfl(my_ind, jm, 64);
        q.x = __shfl(myp.x, jm, 64);
        q.y = __shfl(myp.y, jm, 64);
        q.z = __shfl(myp.z, jm, 64);
        q.w = 0.f;
        warm = true;
    }

    if (lane < KNN) grp_ws[ch * KNN + lane] = my_ind;
    if (lane == 0) {
        pts_ws[ch * 3 + 0] = q.x;
        pts_ws[ch * 3 + 1] = q.y;
        pts_ws[ch * 3 + 2] = q.z;
        idx_ws[ch] = qidx;
        conv_ws[ch] = conv;
    }
}

// ---------------------------------------------------------------------------
// Order: stable rank by (conv, s) via 17-bin counting (verified)
// ---------------------------------------------------------------------------
__global__ __launch_bounds__(1024) void order_kernel(
    const float* __restrict__ pts_ws, const int* __restrict__ idx_ws,
    const int* __restrict__ grp_ws, const int* __restrict__ conv_ws,
    float* __restrict__ out) {
    const int b = (int)blockIdx.x;
    const int s = (int)threadIdx.x;
    const int w = s >> 6, l = s & 63;
    __shared__ int wavecnt[16][MAXIT + 1];
    __shared__ int binbase[MAXIT + 1];
    const size_t ch = (size_t)b * SCH + s;
    const int c = conv_ws[ch];
    int rw = 0;
#pragma unroll
    for (int v = 0; v <= MAXIT; ++v) {
        ull bal = __ballot(c == v);
        if (l == 0) wavecnt[w][v] = (int)__popcll(bal);
        if (c == v) rw = (int)__popcll(bal & ((1ull << l) - 1ull));
    }
    __syncthreads();
    if (s == 0) {
        int acc = 0;
        for (int v = 0; v <= MAXIT; ++v) {
            int t = 0;
            for (int w2 = 0; w2 < 16; ++w2) t += wavecnt[w2][v];
            binbase[v] = acc;
            acc += t;
        }
    }
    __syncthreads();
    int pos = binbase[c] + rw;
    for (int w2 = 0; w2 < w; ++w2) pos += wavecnt[w2][c];

    float* __restrict__ C  = out;                              // (B,S,3)
    float* __restrict__ I1 = out + (size_t)BATCH * SCH * 3;    // (B,S)
    float* __restrict__ I2 = I1 + (size_t)BATCH * SCH;         // (B,S,K)
    const size_t o = (size_t)b * SCH + pos;
    C[o * 3 + 0] = pts_ws[ch * 3 + 0];
    C[o * 3 + 1] = pts_ws[ch * 3 + 1];
    C[o * 3 + 2] = pts_ws[ch * 3 + 2];
    I1[o] = (float)idx_ws[ch];
#pragma unroll
    for (int k = 0; k < KNN; ++k) I2[o * KNN + k] = (float)grp_ws[ch * KNN + k];
}

extern "C" void kernel_launch(void* const* d_in, const int* in_sizes, int n_in,
                              void* d_out, int out_size, void* d_ws, size_t ws_size,
                              hipStream_t stream) {
    const float* xyz    = (const float*)d_in[0];  // (8,8192,3) f32
    const float* center = (const float*)d_in[1];  // (8,1024,3) f32
    const int*   idx_in = (const int*)d_in[2];    // (8,1024)   i32
    float* out = (float*)d_out;

    // workspace layout (~3.6 MB)
    char* wp = (char*)d_ws;
    vf4* pc4     = (vf4*)wp;  wp += (size_t)BATCH * NPTS * sizeof(vf4);   // 1 MB
    vf4* sortedP = (vf4*)wp;  wp += (size_t)BATCH * NPTS * sizeof(vf4);   // 1 MB
    vf4* bC      = (vf4*)wp;  wp += (size_t)BATCH * NGRP * sizeof(vf4);   // 16 KB
    vf4* bH      = (vf4*)wp;  wp += (size_t)BATCH * NGRP * sizeof(vf4);   // 16 KB
    int* counts  = (int*)wp;  wp += (size_t)BATCH * NCELL * 4;            // 128 KB
    int* cursor  = (int*)wp;  wp += (size_t)BATCH * NCELL * 4;            // 128 KB
    float* pts_ws = (float*)wp; wp += (size_t)BATCH * SCH * 3 * 4;
    int*   idx_ws = (int*)wp;   wp += (size_t)BATCH * SCH * 4;
    int*   grp_ws = (int*)wp;   wp += (size_t)BATCH * SCH * KNN * 4;      // 1 MB
    int*   conv_ws = (int*)wp;

    hipMemsetAsync(counts, 0, (size_t)BATCH * NCELL * 4, stream);
    prep_kernel<<<(BATCH * NPTS + 255) / 256, 256, 0, stream>>>(xyz, pc4, counts);
    scan_kernel<<<BATCH, 1024, 0, stream>>>(counts, cursor);
    scatter_kernel<<<(BATCH * NPTS + 255) / 256, 256, 0, stream>>>(pc4, cursor, sortedP);
    bbox_kernel<<<(BATCH * NGRP * 64) / 256, 256, 0, stream>>>(sortedP, bC, bH);

    const int chains = BATCH * SCH;                 // 8192 waves, 1 per chain
    refine_kernel<<<chains * 64 / 256, 256, 0, stream>>>(
        pc4, sortedP, bC, bH, center, idx_in, pts_ws, idx_ws, grp_ws, conv_ws);
    order_kernel<<<BATCH, SCH, 0, stream>>>(pts_ws, idx_ws, grp_ws, conv_ws, out);
}